// Round 7
// baseline (699.426 us; speedup 1.0000x reference)
//
#include <hip/hip_runtime.h>
#include <hip/hip_cooperative_groups.h>
#include <math.h>

namespace cg = cooperative_groups;

#define NQ    8192
#define NPTS  32768
#define KNN   64
#define GRIDD 16
#define NCELL 4096          // 16^3 cells, h=0.5 over [-4,4)
#define CAP   224           // per-query candidate capacity (E=110)

// ---- ws layout (4B elements) ----
#define WS_CNT   0          // 4096
#define WS_QCNT  4096       // 4096
#define WS_START 8192       // 4097
#define WS_X     12292      // 32768 (16B aligned)
#define WS_Y     45060
#define WS_Z     77828
#define WS_I     110596
#define WS_QX    143364     // 8192
#define WS_QY    151556
#define WS_QZ    159748
#define WS_QI    167940
#define WS_TAU   176132
#define WS_TOT_C 184324     // tier C total (737,296 B) — no FS
#define WS_FS    184324     // 4,194,304 floats (16B aligned)
#define WS_TOT_A 4378628    // tier A total (~17.51 MB)

__device__ __forceinline__ int mbcnt64(unsigned long long m) {
  return __builtin_amdgcn_mbcnt_hi((unsigned)(m >> 32),
         __builtin_amdgcn_mbcnt_lo((unsigned)m, 0));
}
__device__ __forceinline__ int cell1(float v) {
  int c = (int)floorf((v + 4.f) * 2.f);
  return min(GRIDD - 1, max(0, c));
}
__device__ __forceinline__ float norm_cdf(float x) { return 0.5f * erfcf(-x * 0.70710678f); }
// Mass of standard 3D gaussian inside ball radius r centered at distance mu (exact).
__device__ __forceinline__ float ball_mass(float mu, float r) {
  float a = r - mu, b = r + mu;
  float e = __expf(-0.5f * b * b) - __expf(-0.5f * a * a);
  return e / (mu * 2.50662827f) + norm_cdf(a) - norm_cdf(-mu) + norm_cdf(b) - norm_cdf(mu);
}

// ================= phase device functions (grid-strided; any grid size) =================
__device__ void ph_zero(int t, int nt, int* cnt, int* qcnt) {
  for (int i = t; i < NCELL; i += nt) { cnt[i] = 0; qcnt[i] = 0; }
}

__device__ void ph_count(int t, int nt, const float* pos, const float* qpos,
                         int* cnt, int* qcnt) {
  for (int p = t; p < NPTS; p += nt) {
    float x = pos[3 * p], y = pos[3 * p + 1], z = pos[3 * p + 2];
    atomicAdd(&cnt[(cell1(z) * GRIDD + cell1(y)) * GRIDD + cell1(x)], 1);
  }
  for (int q = t; q < NQ; q += nt) {
    float x = qpos[3 * q], y = qpos[3 * q + 1], z = qpos[3 * q + 2];
    atomicAdd(&qcnt[(cell1(z) * GRIDD + cell1(y)) * GRIDD + cell1(x)], 1);
  }
}

// one block, 256 threads: exclusive scan of 4096 ints; hist <- excl (cursor), startOut optional
__device__ void ph_scan_block(int tid, int* hist, int* startOut) {
  __shared__ int wsum[4];
  const int lane = tid & 63, wvl = tid >> 6;
  int loc[16]; int s = 0;
  #pragma unroll
  for (int i = 0; i < 16; ++i) { loc[i] = hist[tid * 16 + i]; s += loc[i]; }
  int sc = s;
  #pragma unroll
  for (int d = 1; d < 64; d <<= 1) { int t2 = __shfl_up(sc, d, 64); if (lane >= d) sc += t2; }
  if (lane == 63) wsum[wvl] = sc;
  __syncthreads();
  int wpre = 0;
  for (int w = 0; w < wvl; ++w) wpre += wsum[w];
  int excl = wpre + sc - s;
  #pragma unroll
  for (int i = 0; i < 16; ++i) {
    if (startOut) startOut[tid * 16 + i] = excl;
    hist[tid * 16 + i] = excl;
    excl += loc[i];
  }
  if (tid == 255 && startOut) startOut[NCELL] = excl;
}

__device__ void ph_scatter(int t, int nt, const float* pos, const float* qpos,
                           int* cur, int* qcur,
                           float* X, float* Y, float* Z, int* I,
                           float* QX, float* QY, float* QZ, int* QI, float* tauS) {
  for (int p = t; p < NPTS; p += nt) {
    float x = pos[3 * p], y = pos[3 * p + 1], z = pos[3 * p + 2];
    int c = (cell1(z) * GRIDD + cell1(y)) * GRIDD + cell1(x);
    int j = atomicAdd(&cur[c], 1);
    X[j] = x; Y[j] = y; Z[j] = z; I[j] = p;
  }
  for (int q = t; q < NQ; q += nt) {
    float x = qpos[3 * q], y = qpos[3 * q + 1], z = qpos[3 * q + 2];
    int c = (cell1(z) * GRIDD + cell1(y)) * GRIDD + cell1(x);
    int j = atomicAdd(&qcur[c], 1);
    QX[j] = x; QY[j] = y; QZ[j] = z; QI[j] = q;
    float b2 = x * x + y * y + z * z;
    float mu = fmaxf(sqrtf(b2), 0.05f);
    const float target = 110.0f / 32768.0f;
    float lo = 0.f, hi = mu + 8.f;
    for (int i = 0; i < 16; ++i) {
      float r = 0.5f * (lo + hi);
      if (ball_mass(mu, r) < target) lo = r; else hi = r;
    }
    tauS[j] = hi * hi;
  }
}

__device__ void ph_fscopy(int t, int nt, const float* feat, const int* I, float* FS) {
  for (int u = t; u < NPTS * 16; u += nt) {
    const int j = u >> 4, part = u & 15;
    const float4* src = (const float4*)(feat + ((size_t)I[j] << 7));
    float4* dst = (float4*)(FS + ((size_t)j << 7));
    dst[part] = src[part];
    dst[part + 16] = src[part + 16];
  }
}

template<bool SF>
__device__ void ph_main(int bid, int nblk,
    const float* __restrict__ feat, const float* __restrict__ FS,
    const int* __restrict__ start,
    const float* __restrict__ X, const float* __restrict__ Y, const float* __restrict__ Z,
    const int* __restrict__ I,
    const float* __restrict__ QX, const float* __restrict__ QY, const float* __restrict__ QZ,
    const int* __restrict__ QI, const float* __restrict__ tauS,
    float* __restrict__ out) {

  __shared__ uint2 sCand[4][CAP];
  __shared__ uint2 sSel[4][KNN];

  const int tid = threadIdx.x, lane = tid & 63, wvl = tid >> 6;
  const int vb = (bid & 7) * (nblk >> 3) + (bid >> 3);   // XCD swizzle (nblk % 8 == 0)
  const int nwv = nblk * 4;

  for (int qs = vb * 4 + wvl; qs < NQ; qs += nwv) {
    const float qx = QX[qs], qy = QY[qs], qz = QZ[qs];
    const int gq = QI[qs];
    float tau = tauS[qs];
    float tlo = 0.f, thi = -1.f;
    int m = 0;

    for (int attempt = 0; attempt < 16; ++attempt) {
      m = 0;
      const float r = sqrtf(tau);
      const int xlo = cell1(qx - r), xhi = cell1(qx + r);
      const int ylo = cell1(qy - r), yhi = cell1(qy + r);
      const int zlo = cell1(qz - r), zhi = cell1(qz + r);
      for (int cz = zlo; cz <= zhi; ++cz) {
        for (int cy = ylo; cy <= yhi; ++cy) {
          const int row = (cz * GRIDD + cy) * GRIDD;
          const int rs = start[row + xlo];
          const int re = start[row + xhi + 1];
          for (int j0 = rs; j0 < re; j0 += 64) {
            const int j = j0 + lane;
            float d = 3.4e38f;
            if (j < re) {
              float dx = X[j] - qx, dy = Y[j] - qy, dz = Z[j] - qz;
              d = fmaf(dx, dx, fmaf(dy, dy, dz * dz));
            }
            const bool h = d < tau;
            const unsigned long long msk = __ballot(h);
            if (msk) {
              const int p = m + mbcnt64(msk);
              if (h && p < CAP) {
                const unsigned pid = SF ? (unsigned)j : (unsigned)I[j];
                sCand[wvl][p] = make_uint2(__float_as_uint(d), pid);
              }
              m += (int)__popcll(msk);
            }
          }
        }
      }
      if (m >= KNN && m <= CAP) break;
      if (m < KNN) { tlo = tau; tau = (thi < 0.f) ? tau * 2.5f : 0.5f * (tau + thi); }
      else         { thi = tau; tau = 0.5f * (tlo + tau); }
    }

    const int mm = min(m, CAP);
    const int NS = (mm + 63) >> 6;
    unsigned k[4], id[4];
    #pragma unroll
    for (int s = 0; s < 4; ++s) {
      k[s] = 0xFFFFFFFFu; id[s] = 0u;
      if (s < NS) {
        const int g = s * 64 + lane;
        if (g < mm) { uint2 kv = sCand[wvl][g]; k[s] = kv.x; id[s] = kv.y; }
      }
    }
    sSel[wvl][lane] = make_uint2(0u, 0u);

    if (mm > KNN) {
      unsigned lo = 0u, hi = __float_as_uint(tau);
      while (lo < hi) {
        const unsigned mid = lo + ((hi - lo) >> 1);
        int c = 0;
        #pragma unroll
        for (int s = 0; s < 4; ++s)
          if (s < NS) c += (int)__popcll(__ballot(k[s] <= mid));
        if (c >= KNN) hi = mid; else lo = mid + 1;
      }
      const unsigned K = lo;
      int fill = 0;
      #pragma unroll
      for (int s = 0; s < 4; ++s) {
        if (s < NS) {
          const bool lt = k[s] < K;
          const unsigned long long msk = __ballot(lt);
          if (msk) {
            const int p = fill + mbcnt64(msk);
            if (lt) {
              float dv = __uint_as_float(k[s]);
              float w_ = 1.f / (sqrtf(fmaxf(dv, 1e-12f)) + 1e-5f);
              sSel[wvl][p] = make_uint2(id[s], __float_as_uint(w_));
            }
            fill += (int)__popcll(msk);
          }
        }
      }
      #pragma unroll
      for (int s = 0; s < 4; ++s) {
        if (s < NS) {
          const bool eq = (k[s] == K);
          const unsigned long long msk = __ballot(eq);
          if (msk) {
            const int p = fill + mbcnt64(msk);
            if (eq && p < KNN) {
              float dv = __uint_as_float(k[s]);
              float w_ = 1.f / (sqrtf(fmaxf(dv, 1e-12f)) + 1e-5f);
              sSel[wvl][p] = make_uint2(id[s], __float_as_uint(w_));
            }
            fill += (int)__popcll(msk);
          }
        }
      }
    } else {
      #pragma unroll
      for (int s = 0; s < 4; ++s) {
        if (s < NS) {
          const int g = s * 64 + lane;
          if (g < mm) {
            float dv = __uint_as_float(k[s]);
            float w_ = 1.f / (sqrtf(fmaxf(dv, 1e-12f)) + 1e-5f);
            sSel[wvl][g] = make_uint2(id[s], __float_as_uint(w_));
          }
        }
      }
    }

    // gather: float4/lane, 2 rows per iter, shfl-combine halves
    const float* FB = SF ? FS : feat;
    const int half = lane >> 5;
    const int c4 = lane & 31;
    float4 acc = make_float4(0.f, 0.f, 0.f, 0.f);
    #pragma unroll 4
    for (int jj = 0; jj < 32; ++jj) {
      const uint2 pr = sSel[wvl][(jj << 1) + half];
      const float w = __uint_as_float(pr.y);
      const float4 f = *(const float4*)(FB + ((size_t)pr.x << 7) + (c4 << 2));
      acc.x = fmaf(w, f.x, acc.x); acc.y = fmaf(w, f.y, acc.y);
      acc.z = fmaf(w, f.z, acc.z); acc.w = fmaf(w, f.w, acc.w);
    }
    const float ox = acc.x + __shfl_xor(acc.x, 32, 64);
    const float oy = acc.y + __shfl_xor(acc.y, 32, 64);
    const float oz = acc.z + __shfl_xor(acc.z, 32, 64);
    const float ow = acc.w + __shfl_xor(acc.w, 32, 64);
    if (lane < 32) {
      *(float4*)(out + ((size_t)gq << 7) + (c4 << 2)) = make_float4(ox, oy, oz, ow);
    }
  }
}

// ================= fused cooperative kernel =================
template<bool SF>
__global__ __launch_bounds__(256, 8) void k_fused(
    const float* pos, const float* qpos, const float* feat,
    int* cnt, int* qcnt, int* start,
    float* X, float* Y, float* Z, int* I,
    float* QX, float* QY, float* QZ, int* QI, float* tauS, float* FS, float* out) {
  cg::grid_group g = cg::this_grid();
  const int t  = blockIdx.x * 256 + threadIdx.x;
  const int nt = gridDim.x * 256;
  ph_zero(t, nt, cnt, qcnt);
  g.sync();
  ph_count(t, nt, pos, qpos, cnt, qcnt);
  g.sync();
  if (blockIdx.x == 0)      ph_scan_block(threadIdx.x, cnt, start);
  else if (blockIdx.x == 1) ph_scan_block(threadIdx.x, qcnt, nullptr);
  g.sync();
  ph_scatter(t, nt, pos, qpos, cnt, qcnt, X, Y, Z, I, QX, QY, QZ, QI, tauS);
  g.sync();
  if (SF) { ph_fscopy(t, nt, feat, I, FS); g.sync(); }
  ph_main<SF>(blockIdx.x, gridDim.x, feat, FS, start, X, Y, Z, I, QX, QY, QZ, QI, tauS, out);
}

// ================= fallback: same phases as separate dispatches =================
__global__ void k_p0(int* cnt, int* qcnt) {
  ph_zero(blockIdx.x * 256 + threadIdx.x, gridDim.x * 256, cnt, qcnt);
}
__global__ void k_p1(const float* pos, const float* qpos, int* cnt, int* qcnt) {
  ph_count(blockIdx.x * 256 + threadIdx.x, gridDim.x * 256, pos, qpos, cnt, qcnt);
}
__global__ void k_p2(int* cnt, int* qcnt, int* start) {
  if (blockIdx.x == 0) ph_scan_block(threadIdx.x, cnt, start);
  else                 ph_scan_block(threadIdx.x, qcnt, nullptr);
}
__global__ void k_p3(const float* pos, const float* qpos, int* cnt, int* qcnt,
                     float* X, float* Y, float* Z, int* I,
                     float* QX, float* QY, float* QZ, int* QI, float* tauS) {
  ph_scatter(blockIdx.x * 256 + threadIdx.x, gridDim.x * 256, pos, qpos, cnt, qcnt,
             X, Y, Z, I, QX, QY, QZ, QI, tauS);
}
__global__ void k_p3b(const float* feat, const int* I, float* FS) {
  ph_fscopy(blockIdx.x * 256 + threadIdx.x, gridDim.x * 256, feat, I, FS);
}
template<bool SF>
__global__ __launch_bounds__(256, 8) void k_p4(
    const float* feat, const float* FS, const int* start,
    const float* X, const float* Y, const float* Z, const int* I,
    const float* QX, const float* QY, const float* QZ, const int* QI,
    const float* tauS, float* out) {
  ph_main<SF>(blockIdx.x, gridDim.x, feat, FS, start, X, Y, Z, I, QX, QY, QZ, QI, tauS, out);
}

extern "C" void kernel_launch(void* const* d_in, const int* in_sizes, int n_in,
                              void* d_out, int out_size, void* d_ws, size_t ws_size,
                              hipStream_t stream) {
  const float* qpos = (const float*)d_in[0];   // [8192,3]
  const float* feat = (const float*)d_in[1];   // [32768,128]
  const float* pos  = (const float*)d_in[2];   // [32768,3]
  float* out = (float*)d_out;                  // [8192,128]

  float* wsf = (float*)d_ws;
  int*   wsi = (int*)d_ws;
  int*   cnt  = wsi + WS_CNT;   int* qcnt = wsi + WS_QCNT;  int* start = wsi + WS_START;
  float* X = wsf + WS_X;  float* Y = wsf + WS_Y;  float* Z = wsf + WS_Z;
  int*   I = wsi + WS_I;
  float* QX = wsf + WS_QX; float* QY = wsf + WS_QY; float* QZ = wsf + WS_QZ;
  int*   QI = wsi + WS_QI; float* tauS = wsf + WS_TAU;
  float* FS = wsf + WS_FS;
  const bool useFS = ws_size >= (size_t)WS_TOT_A * 4;

  // cooperative path: one dispatch, grid sized to exact residency
  int occ = 0;
  hipError_t oe = useFS
    ? hipOccupancyMaxActiveBlocksPerMultiprocessor(&occ, (const void*)k_fused<true>, 256, 0)
    : hipOccupancyMaxActiveBlocksPerMultiprocessor(&occ, (const void*)k_fused<false>, 256, 0);
  bool coop_ok = false;
  if (oe == hipSuccess && occ > 0) {
    int nblk = occ * 256;
    if (nblk > 2048) nblk = 2048;
    void* args[] = { (void*)&pos, (void*)&qpos, (void*)&feat,
                     (void*)&cnt, (void*)&qcnt, (void*)&start,
                     (void*)&X, (void*)&Y, (void*)&Z, (void*)&I,
                     (void*)&QX, (void*)&QY, (void*)&QZ, (void*)&QI,
                     (void*)&tauS, (void*)&FS, (void*)&out };
    hipError_t le = hipLaunchCooperativeKernel(
        useFS ? (const void*)k_fused<true> : (const void*)k_fused<false>,
        dim3(nblk), dim3(256), args, 0, stream);
    coop_ok = (le == hipSuccess);
  }

  if (!coop_ok) {
    k_p0<<<dim3(16), dim3(256), 0, stream>>>(cnt, qcnt);
    k_p1<<<dim3(160), dim3(256), 0, stream>>>(pos, qpos, cnt, qcnt);
    k_p2<<<dim3(2), dim3(256), 0, stream>>>(cnt, qcnt, start);
    k_p3<<<dim3(160), dim3(256), 0, stream>>>(pos, qpos, cnt, qcnt, X, Y, Z, I, QX, QY, QZ, QI, tauS);
    if (useFS) {
      k_p3b<<<dim3(2048), dim3(256), 0, stream>>>(feat, I, FS);
      k_p4<true><<<dim3(2048), dim3(256), 0, stream>>>(feat, FS, start, X, Y, Z, I,
                                                       QX, QY, QZ, QI, tauS, out);
    } else {
      k_p4<false><<<dim3(2048), dim3(256), 0, stream>>>(feat, FS, start, X, Y, Z, I,
                                                        QX, QY, QZ, QI, tauS, out);
    }
  }
}

// Round 8
// 161.149 us; speedup vs baseline: 4.3402x; 4.3402x over previous
//
#include <hip/hip_runtime.h>
#include <math.h>

#define NQ    8192
#define NPTS  32768
#define KNN   64
#define GRIDD 16
#define NCELL 4096          // 16^3 cells, h=0.5 over [-4,4)
#define CAP   224           // per-query candidate capacity (E=110)
#define NBLKM 2048          // main: 4 waves/block, 1 query/wave

// ---- ws layout (4B elements) ----
#define WS_CNT   0          // 4096
#define WS_QCNT  4096       // 4096
#define WS_START 8192       // 4097
#define WS_X     12292      // 32768 (16B aligned)
#define WS_Y     45060
#define WS_Z     77828
#define WS_I     110596
#define WS_QX    143364     // 8192
#define WS_QY    151556
#define WS_QZ    159748
#define WS_QI    167940
#define WS_TAU   176132
#define WS_TOT_C 184324     // tier C total (737,296 B) — no FS
#define WS_FS    184324     // 4,194,304 floats (16B aligned)
#define WS_TOT_A 4378628    // tier A total (~17.51 MB)

__device__ __forceinline__ int mbcnt64(unsigned long long m) {
  return __builtin_amdgcn_mbcnt_hi((unsigned)(m >> 32),
         __builtin_amdgcn_mbcnt_lo((unsigned)m, 0));
}
__device__ __forceinline__ int cell1(float v) {
  int c = (int)floorf((v + 4.f) * 2.f);
  return min(GRIDD - 1, max(0, c));
}
__device__ __forceinline__ float norm_cdf(float x) { return 0.5f * erfcf(-x * 0.70710678f); }
// Mass of standard 3D gaussian inside ball radius r centered at distance mu (exact).
__device__ __forceinline__ float ball_mass(float mu, float r) {
  float a = r - mu, b = r + mu;
  float e = __expf(-0.5f * b * b) - __expf(-0.5f * a * a);
  return e / (mu * 2.50662827f) + norm_cdf(a) - norm_cdf(-mu) + norm_cdf(b) - norm_cdf(mu);
}

// ============ K1: count points + queries into cell histograms (160 blocks) ============
__global__ void k_count(const float* __restrict__ pos, const float* __restrict__ qpos,
                        int* __restrict__ cnt, int* __restrict__ qcnt) {
  const int t = blockIdx.x * 256 + threadIdx.x, nt = gridDim.x * 256;
  for (int p = t; p < NPTS; p += nt) {
    float x = pos[3 * p], y = pos[3 * p + 1], z = pos[3 * p + 2];
    atomicAdd(&cnt[(cell1(z) * GRIDD + cell1(y)) * GRIDD + cell1(x)], 1);
  }
  for (int q = t; q < NQ; q += nt) {
    float x = qpos[3 * q], y = qpos[3 * q + 1], z = qpos[3 * q + 2];
    atomicAdd(&qcnt[(cell1(z) * GRIDD + cell1(y)) * GRIDD + cell1(x)], 1);
  }
}

// ============ K2: 2 blocks — exclusive scans; hist <- cursor, start kept for points ======
__global__ void k_scan(int* __restrict__ cnt, int* __restrict__ qcnt, int* __restrict__ start) {
  __shared__ int wsum[4];
  int* hist = (blockIdx.x == 0) ? cnt : qcnt;
  int* so   = (blockIdx.x == 0) ? start : nullptr;
  const int tid = threadIdx.x, lane = tid & 63, wvl = tid >> 6;
  int loc[16]; int s = 0;
  #pragma unroll
  for (int i = 0; i < 16; ++i) { loc[i] = hist[tid * 16 + i]; s += loc[i]; }
  int sc = s;
  #pragma unroll
  for (int d = 1; d < 64; d <<= 1) { int t2 = __shfl_up(sc, d, 64); if (lane >= d) sc += t2; }
  if (lane == 63) wsum[wvl] = sc;
  __syncthreads();
  int wpre = 0;
  for (int w = 0; w < wvl; ++w) wpre += wsum[w];
  int excl = wpre + sc - s;
  #pragma unroll
  for (int i = 0; i < 16; ++i) {
    if (so) so[tid * 16 + i] = excl;
    hist[tid * 16 + i] = excl;
    excl += loc[i];
  }
  if (tid == 255 && so) so[NCELL] = excl;
}

// ============ K3: scatter points (+FS row copy) and queries (+tau) (160 blocks) ============
template<bool SF>
__global__ void k_scatter(const float* __restrict__ pos, const float* __restrict__ qpos,
                          const float* __restrict__ feat,
                          int* __restrict__ cur, int* __restrict__ qcur,
                          float* __restrict__ X, float* __restrict__ Y, float* __restrict__ Z,
                          int* __restrict__ I, float* __restrict__ FS,
                          float* __restrict__ QX, float* __restrict__ QY, float* __restrict__ QZ,
                          int* __restrict__ QI, float* __restrict__ tauS) {
  const int t = blockIdx.x * 256 + threadIdx.x, nt = gridDim.x * 256;
  for (int p = t; p < NPTS; p += nt) {
    float x = pos[3 * p], y = pos[3 * p + 1], z = pos[3 * p + 2];
    int c = (cell1(z) * GRIDD + cell1(y)) * GRIDD + cell1(x);
    int j = atomicAdd(&cur[c], 1);
    X[j] = x; Y[j] = y; Z[j] = z; I[j] = p;
    if (SF) {
      const float4* src = (const float4*)(feat + ((size_t)p << 7));
      float4* dst = (float4*)(FS + ((size_t)j << 7));
      #pragma unroll 8
      for (int u = 0; u < 32; ++u) dst[u] = src[u];
    }
  }
  for (int q = t; q < NQ; q += nt) {
    float x = qpos[3 * q], y = qpos[3 * q + 1], z = qpos[3 * q + 2];
    int c = (cell1(z) * GRIDD + cell1(y)) * GRIDD + cell1(x);
    int j = atomicAdd(&qcur[c], 1);
    QX[j] = x; QY[j] = y; QZ[j] = z; QI[j] = q;
    float b2 = x * x + y * y + z * z;
    float mu = fmaxf(sqrtf(b2), 0.05f);
    const float target = 110.0f / 32768.0f;
    float lo = 0.f, hi = mu + 8.f;
    for (int i = 0; i < 16; ++i) {
      float r = 0.5f * (lo + hi);
      if (ball_mass(mu, r) < target) lo = r; else hi = r;
    }
    tauS[j] = hi * hi;
  }
}

// ============ K4: main — one wave per sorted query, XCD-swizzled ============
template<bool SF>
__global__ __launch_bounds__(256, 8) void k_main(
    const float* __restrict__ feat, const float* __restrict__ FS,
    const int* __restrict__ start,
    const float* __restrict__ X, const float* __restrict__ Y, const float* __restrict__ Z,
    const int* __restrict__ I,
    const float* __restrict__ QX, const float* __restrict__ QY, const float* __restrict__ QZ,
    const int* __restrict__ QI, const float* __restrict__ tauS, float* __restrict__ out) {

  __shared__ uint2 sCand[4][CAP];
  __shared__ uint2 sSel[4][KNN];

  const int tid = threadIdx.x, lane = tid & 63, wvl = tid >> 6;
  // XCD swizzle: blocks land round-robin on XCDs (bid%8); give XCD k the
  // contiguous sorted-query range [k*1024,(k+1)*1024) -> compact L2 working set.
  const int vb = (blockIdx.x & 7) * (NBLKM >> 3) + (blockIdx.x >> 3);
  const int qs = vb * 4 + wvl;

  const float qx = QX[qs], qy = QY[qs], qz = QZ[qs];
  const int gq = QI[qs];
  float tau = tauS[qs];
  float tlo = 0.f, thi = -1.f;
  int m = 0;

  // ---- candidate collection over merged x-rows of grid cells ----
  for (int attempt = 0; attempt < 16; ++attempt) {
    m = 0;
    const float r = sqrtf(tau);
    const int xlo = cell1(qx - r), xhi = cell1(qx + r);
    const int ylo = cell1(qy - r), yhi = cell1(qy + r);
    const int zlo = cell1(qz - r), zhi = cell1(qz + r);
    for (int cz = zlo; cz <= zhi; ++cz) {
      for (int cy = ylo; cy <= yhi; ++cy) {
        const int row = (cz * GRIDD + cy) * GRIDD;
        const int rs = start[row + xlo];
        const int re = start[row + xhi + 1];
        for (int j0 = rs; j0 < re; j0 += 64) {
          const int j = j0 + lane;
          float d = 3.4e38f;
          if (j < re) {
            float dx = X[j] - qx, dy = Y[j] - qy, dz = Z[j] - qz;
            d = fmaf(dx, dx, fmaf(dy, dy, dz * dz));
          }
          const bool h = d < tau;
          const unsigned long long msk = __ballot(h);
          if (msk) {
            const int p = m + mbcnt64(msk);
            if (h && p < CAP) {
              const unsigned pid = SF ? (unsigned)j : (unsigned)I[j];
              sCand[wvl][p] = make_uint2(__float_as_uint(d), pid);
            }
            m += (int)__popcll(msk);
          }
        }
      }
    }
    if (m >= KNN && m <= CAP) break;
    if (m < KNN) { tlo = tau; tau = (thi < 0.f) ? tau * 2.5f : 0.5f * (tau + thi); }
    else         { thi = tau; tau = 0.5f * (tlo + tau); }
  }

  // ---- exact top-64 (bisection on nonneg float bits; ballot counting) ----
  const int mm = min(m, CAP);
  const int NS = (mm + 63) >> 6;
  unsigned k[4], id[4];
  #pragma unroll
  for (int s = 0; s < 4; ++s) {
    k[s] = 0xFFFFFFFFu; id[s] = 0u;
    if (s < NS) {
      const int g = s * 64 + lane;
      if (g < mm) { uint2 kv = sCand[wvl][g]; k[s] = kv.x; id[s] = kv.y; }
    }
  }
  sSel[wvl][lane] = make_uint2(0u, 0u);   // padding: id 0, w 0

  if (mm > KNN) {
    unsigned lo = 0u, hi = __float_as_uint(tau);
    while (lo < hi) {
      const unsigned mid = lo + ((hi - lo) >> 1);
      int c = 0;
      #pragma unroll
      for (int s = 0; s < 4; ++s)
        if (s < NS) c += (int)__popcll(__ballot(k[s] <= mid));
      if (c >= KNN) hi = mid; else lo = mid + 1;
    }
    const unsigned K = lo;
    int fill = 0;
    #pragma unroll
    for (int s = 0; s < 4; ++s) {
      if (s < NS) {
        const bool lt = k[s] < K;
        const unsigned long long msk = __ballot(lt);
        if (msk) {
          const int p = fill + mbcnt64(msk);
          if (lt) {
            float dv = __uint_as_float(k[s]);
            float w_ = 1.f / (sqrtf(fmaxf(dv, 1e-12f)) + 1e-5f);
            sSel[wvl][p] = make_uint2(id[s], __float_as_uint(w_));
          }
          fill += (int)__popcll(msk);
        }
      }
    }
    #pragma unroll
    for (int s = 0; s < 4; ++s) {      // ties at K
      if (s < NS) {
        const bool eq = (k[s] == K);
        const unsigned long long msk = __ballot(eq);
        if (msk) {
          const int p = fill + mbcnt64(msk);
          if (eq && p < KNN) {
            float dv = __uint_as_float(k[s]);
            float w_ = 1.f / (sqrtf(fmaxf(dv, 1e-12f)) + 1e-5f);
            sSel[wvl][p] = make_uint2(id[s], __float_as_uint(w_));
          }
          fill += (int)__popcll(msk);
        }
      }
    }
  } else {
    #pragma unroll
    for (int s = 0; s < 4; ++s) {
      if (s < NS) {
        const int g = s * 64 + lane;
        if (g < mm) {
          float dv = __uint_as_float(k[s]);
          float w_ = 1.f / (sqrtf(fmaxf(dv, 1e-12f)) + 1e-5f);
          sSel[wvl][g] = make_uint2(id[s], __float_as_uint(w_));
        }
      }
    }
  }

  // ---- gather: float4/lane, 2 rows per iter, shfl-combine halves ----
  const float* FB = SF ? FS : feat;
  const int half = lane >> 5;
  const int c4 = lane & 31;
  float4 acc = make_float4(0.f, 0.f, 0.f, 0.f);
  #pragma unroll 4
  for (int jj = 0; jj < 32; ++jj) {
    const uint2 pr = sSel[wvl][(jj << 1) + half];
    const float w = __uint_as_float(pr.y);
    const float4 f = *(const float4*)(FB + ((size_t)pr.x << 7) + (c4 << 2));
    acc.x = fmaf(w, f.x, acc.x); acc.y = fmaf(w, f.y, acc.y);
    acc.z = fmaf(w, f.z, acc.z); acc.w = fmaf(w, f.w, acc.w);
  }
  const float ox = acc.x + __shfl_xor(acc.x, 32, 64);
  const float oy = acc.y + __shfl_xor(acc.y, 32, 64);
  const float oz = acc.z + __shfl_xor(acc.z, 32, 64);
  const float ow = acc.w + __shfl_xor(acc.w, 32, 64);
  if (lane < 32) {
    *(float4*)(out + ((size_t)gq << 7) + (c4 << 2)) = make_float4(ox, oy, oz, ow);
  }
}

extern "C" void kernel_launch(void* const* d_in, const int* in_sizes, int n_in,
                              void* d_out, int out_size, void* d_ws, size_t ws_size,
                              hipStream_t stream) {
  const float* qpos = (const float*)d_in[0];   // [8192,3]
  const float* feat = (const float*)d_in[1];   // [32768,128]
  const float* pos  = (const float*)d_in[2];   // [32768,3]
  float* out = (float*)d_out;                  // [8192,128]

  float* wsf = (float*)d_ws;
  int*   wsi = (int*)d_ws;
  int*   cnt  = wsi + WS_CNT;   int* qcnt = wsi + WS_QCNT;  int* start = wsi + WS_START;
  float* X = wsf + WS_X;  float* Y = wsf + WS_Y;  float* Z = wsf + WS_Z;
  int*   I = wsi + WS_I;
  float* QX = wsf + WS_QX; float* QY = wsf + WS_QY; float* QZ = wsf + WS_QZ;
  int*   QI = wsi + WS_QI; float* tauS = wsf + WS_TAU;
  float* FS = wsf + WS_FS;
  const bool useFS = ws_size >= (size_t)WS_TOT_A * 4;

  (void)hipMemsetAsync(cnt, 0, 2 * NCELL * sizeof(int), stream);   // cnt + qcnt adjacent
  k_count<<<dim3(160), dim3(256), 0, stream>>>(pos, qpos, cnt, qcnt);
  k_scan<<<dim3(2), dim3(256), 0, stream>>>(cnt, qcnt, start);
  if (useFS) {
    k_scatter<true><<<dim3(160), dim3(256), 0, stream>>>(pos, qpos, feat, cnt, qcnt,
                                                         X, Y, Z, I, FS, QX, QY, QZ, QI, tauS);
    k_main<true><<<dim3(NBLKM), dim3(256), 0, stream>>>(feat, FS, start, X, Y, Z, I,
                                                        QX, QY, QZ, QI, tauS, out);
  } else {
    k_scatter<false><<<dim3(160), dim3(256), 0, stream>>>(pos, qpos, feat, cnt, qcnt,
                                                          X, Y, Z, I, FS, QX, QY, QZ, QI, tauS);
    k_main<false><<<dim3(NBLKM), dim3(256), 0, stream>>>(feat, FS, start, X, Y, Z, I,
                                                         QX, QY, QZ, QI, tauS, out);
  }
}